// Round 8
// baseline (56.391 us; speedup 1.0000x reference)
//
#include <hip/hip_runtime.h>
#include <hip/hip_fp16.h>

// ApproxConv2d via 256x256 LUT (approximate multiplier).
// out[b,o,y,x] = sum_{c,ky,kx} lut[ qx(b,c,y+ky-1,x+kx-1)*256 + qw(o,c,ky,kx) ] + bias[o]
// qx/qw = clip(rint(v*64), -128, 127) + 128; padding -> qx=128 -> lut row 128 = 0.
//
// v8: o-QUAD b64 tap rows. T[quad][c][ky][qx] = 24B = 3 taps x
// {h(o0)|h(o1), h(o2)|h(o3)}. One ds_read_b64 feeds 4 MACs (2 __hadd2) --
// half the DS instructions of v7's b32 o-pair on the measured-saturated LDS
// pipe. 24B row stride -> b64 starts spread over 16 even bank slots (v6
// measured ~15cyc incl conflicts). Block = (quad, b, image-quarter):
// 2 parities x 128 threads, 2-px strips; per t stage channels {2t, 2t+1}
// (36864B contiguous, global_load_lds w=16), 2 barriers / 2 channels.
// fp16 accumulate in __half2 pairs, migrated to f32 every 2 channels.

#define NT 256

__device__ __forceinline__ int quantize(float v) {
    // clip(rint(v*64), -128, 127) + 128; rintf = round-half-to-even = jnp.round
    int q = (int)rintf(v * 64.0f);
    q = q < -128 ? -128 : q;
    q = q > 127 ? 127 : q;
    return q + 128;
}

__device__ __forceinline__ void gll16(const void* g, void* l) {
    __builtin_amdgcn_global_load_lds(
        (const __attribute__((address_space(1))) unsigned int*)g,
        (__attribute__((address_space(3))) unsigned int*)l, 16, 0, 0);
}

// -------- build: T[quad][c][ky][qx] 24B o-quad rows -------------------------
// 512 blocks = (quad, 8-qx-row slice). Full-width LUT band, no outliers.
__global__ __launch_bounds__(NT, 2)
void build_T4(const float* __restrict__ w, const float* __restrict__ lut,
              unsigned int* __restrict__ T)
{
    __shared__ float band[8 * 257];          // 8 lut rows, +1 pad
    __shared__ unsigned char qw4[4][576];

    const int tid = threadIdx.x;
    const int quad = blockIdx.x >> 5;        // 0..15
    const int q0 = (blockIdx.x & 31) << 3;   // qx slice base (8 rows)

    for (int i = tid; i < 4 * 576; i += NT) {
        int oo = i / 576, idx = i - oo * 576;
        qw4[oo][idx] = (unsigned char)quantize(w[(quad * 4 + oo) * 576 + idx]);
    }
    for (int i = tid; i < 8 * 256; i += NT) {
        int r = i >> 8, c2 = i & 255;
        band[r * 257 + c2] = lut[(q0 + r) * 256 + c2];
    }
    __syncthreads();

    // 64c x 3ky x 8qx = 1536 items; each writes one 24B row (3x uint2)
    for (int it = 0; it < 6; ++it) {
        int idx = it * NT + tid;
        int c = idx / 24;
        int rem = idx - c * 24;
        int ky = rem >> 3;
        int qxl = rem & 7;
        const float* brow = band + qxl * 257;
        const int wb = c * 9 + ky * 3;
        unsigned int* dst =
            T + (((size_t)(quad * 64 + c) * 3 + ky) * 256 + q0 + qxl) * 6;
        #pragma unroll
        for (int k = 0; k < 3; ++k) {
            unsigned int h0 = __half_as_ushort(__float2half(brow[qw4[0][wb + k]]));
            unsigned int h1 = __half_as_ushort(__float2half(brow[qw4[1][wb + k]]));
            unsigned int h2 = __half_as_ushort(__float2half(brow[qw4[2][wb + k]]));
            unsigned int h3 = __half_as_ushort(__float2half(brow[qw4[3][wb + k]]));
            *(uint2*)(dst + k * 2) = make_uint2(h0 | (h1 << 16), h2 | (h3 << 16));
        }
    }
}

// -------- main: block = (quad, b, quarter); 2 parities x 128 thr, 2-px ------
__global__ __launch_bounds__(NT, 2)
void approx_main(const float* __restrict__ x, const unsigned int* __restrict__ T,
                 const float* __restrict__ bias, float* __restrict__ out)
{
    __shared__ __align__(16) unsigned char Ts[36864];  // 2 channels' T
    __shared__ unsigned int plane[2][2][100];          // [parity][buf] 10r x 40B

    const int tid = threadIdx.x;
    const int bid = blockIdx.x;
    const int quad = bid & 15;               // XCD = bid%8 = quad%8
    const int g = bid >> 4;                  // 0..31
    const int b = g >> 2;
    const int qt = g & 3;                    // image quarter (8 output rows)

    const int p = tid >> 7;                  // channel parity (c mod 2)
    const int lt = tid & 127;
    const int yl = lt >> 4;                  // local row 0..7
    const int x0 = (lt & 15) << 1;           // 2-px strip base col
    const int yg = qt * 8 + yl;

    const char* Tg = (const char*)T + (size_t)quad * 1179648;  // 64*3*256*24
    const float* xb = x + (size_t)b * 65536;

    // plane row r <-> input row qt*8 + r - 1 (r=0 top halo, r=9 bottom halo)
    for (int i = tid; i < 400; i += NT) ((unsigned int*)plane)[i] = 0x80808080u;

    // halo assignment for lt<64: hr=0 top (input row qt*8-1), hr=1 bottom
    int hvalid = 0, hrow = 0, hpr = 0;
    float xh = 0.f;
    if (lt < 64) {
        int hr = lt >> 5;
        int grow = qt * 8 + (hr ? 8 : -1);
        hvalid = (grow >= 0 && grow < 32);
        hrow = grow;
        hpr = hr ? 9 : 0;
        if (hvalid) xh = xb[p * 1024 + hrow * 32 + (lt & 31)];
    }
    // prologue pixel prefetch for c = p
    float2 xv = *(const float2*)(xb + p * 1024 + yg * 32 + x0);

    __syncthreads();   // plane init complete

    __half2 z2 = __float2half2_rn(0.f);
    __half2 ah00 = z2, ah01 = z2, ah10 = z2, ah11 = z2;  // [px][o-pair]
    float a32[2][4] = {{0.f, 0.f, 0.f, 0.f}, {0.f, 0.f, 0.f, 0.f}};

    for (int t = 0; t < 32; ++t) {
        const int buf = t & 1;
        // write-late: this parity's plane for c = 2t+p
        unsigned char* pb = (unsigned char*)plane[p][buf];
        int qa = quantize(xv.x), qb = quantize(xv.y);
        *(unsigned short*)(pb + (yl + 1) * 40 + 4 + x0) =
            (unsigned short)(qa | (qb << 8));
        if (lt < 64 && hvalid) pb[hpr * 40 + 4 + (lt & 31)] = (unsigned char)quantize(xh);

        // stage channels {2t, 2t+1}: 36864B contiguous
        {
            const char* src = Tg + (size_t)t * 36864 + tid * 16;
            char* dst = (char*)Ts + tid * 16;
            #pragma unroll
            for (int k = 0; k < 9; ++k) gll16(src + k * 4096, dst + k * 4096);
        }
        // issue-early: next channel's pixels
        if (t < 31) {
            const int cn = 2 * (t + 1) + p;
            xv = *(const float2*)(xb + cn * 1024 + yg * 32 + x0);
            if (lt < 64 && hvalid) xh = xb[cn * 1024 + hrow * 32 + (lt & 31)];
        }
        __syncthreads();   // gll drained into Ts; planes visible

        // compute channel c = 2t + p
        const unsigned int* pl = plane[p][buf];
        const char* Tp = (const char*)Ts + p * 18432;
        #pragma unroll
        for (int ky = 0; ky < 3; ++ky) {
            const int pbase = (yl + ky) * 10;
            const int j0 = (x0 + 3) >> 2;
            unsigned int wlo = pl[pbase + j0];
            unsigned int whi = pl[pbase + j0 + 1];
            // extract qx bytes of input cols x0-1..x0+2 (plane col j at byte 4+j)
            unsigned long long dv = ((unsigned long long)whi << 32) | wlo;
            unsigned int qbts = (unsigned int)(dv >> (((x0 + 3) & 3) * 8));
            int m0 = (int)(qbts & 255u), m1 = (int)((qbts >> 8) & 255u);
            int m2 = (int)((qbts >> 16) & 255u), m3 = (int)(qbts >> 24);
            const char* Tk = Tp + ky * 6144;
            // px0 (col x0): tap kx from row m_kx; px1: tap kx from row m_{kx+1}
            uint2 A = *(const uint2*)(Tk + m0 * 24);       // px0 k0
            uint2 Bv = *(const uint2*)(Tk + m1 * 24 + 8);  // px0 k1
            uint2 Cv = *(const uint2*)(Tk + m2 * 24 + 16); // px0 k2
            uint2 D = *(const uint2*)(Tk + m1 * 24);       // px1 k0
            uint2 E = *(const uint2*)(Tk + m2 * 24 + 8);   // px1 k1
            uint2 F = *(const uint2*)(Tk + m3 * 24 + 16);  // px1 k2
            ah00 = __hadd2(ah00, *(__half2*)&A.x);  ah01 = __hadd2(ah01, *(__half2*)&A.y);
            ah00 = __hadd2(ah00, *(__half2*)&Bv.x); ah01 = __hadd2(ah01, *(__half2*)&Bv.y);
            ah00 = __hadd2(ah00, *(__half2*)&Cv.x); ah01 = __hadd2(ah01, *(__half2*)&Cv.y);
            ah10 = __hadd2(ah10, *(__half2*)&D.x);  ah11 = __hadd2(ah11, *(__half2*)&D.y);
            ah10 = __hadd2(ah10, *(__half2*)&E.x);  ah11 = __hadd2(ah11, *(__half2*)&E.y);
            ah10 = __hadd2(ah10, *(__half2*)&F.x);  ah11 = __hadd2(ah11, *(__half2*)&F.y);
        }
        // migrate fp16 partials to f32 every 2 channels (18-term chunks)
        if (t & 1) {
            a32[0][0] += __low2float(ah00); a32[0][1] += __high2float(ah00);
            a32[0][2] += __low2float(ah01); a32[0][3] += __high2float(ah01);
            a32[1][0] += __low2float(ah10); a32[1][1] += __high2float(ah10);
            a32[1][2] += __low2float(ah11); a32[1][3] += __high2float(ah11);
            ah00 = z2; ah01 = z2; ah10 = z2; ah11 = z2;
        }
        __syncthreads();   // compute done before next stage overwrites Ts
    }

    // cross-parity reduce via Ts (4KB), then bias + store
    float* red = (float*)Ts;
    if (p) {
        #pragma unroll
        for (int px = 0; px < 2; ++px)
            #pragma unroll
            for (int oo = 0; oo < 4; ++oo)
                red[lt * 8 + px * 4 + oo] = a32[px][oo];
    }
    __syncthreads();
    if (!p) {
        const int o0 = quad * 4;
        #pragma unroll
        for (int oo = 0; oo < 4; ++oo) {
            float bo = bias[o0 + oo];
            float2 r;
            r.x = a32[0][oo] + red[lt * 8 + oo]     + bo;
            r.y = a32[1][oo] + red[lt * 8 + 4 + oo] + bo;
            *(float2*)(out + ((size_t)b * 64 + o0 + oo) * 1024 + yg * 32 + x0) = r;
        }
    }
}

// -------- fallback (proven v1, 98us): used if ws too small ------------------
#define BW1 61
__global__ __launch_bounds__(NT, 2)
void approxconv2d_v1(const float* __restrict__ x,
                     const float* __restrict__ w,
                     const float* __restrict__ bias,
                     const float* __restrict__ lut,
                     float* __restrict__ out)
{
    __shared__ float band[256 * BW1];
    __shared__ unsigned int plane[340];
    __shared__ unsigned char qwrow[576];
    __shared__ int s_min;

    const int tid = threadIdx.x;
    const int bid = blockIdx.x;
    const int b = bid >> 6;
    const int o = bid & 63;

    if (tid == 0) s_min = 255;
    for (int i = tid; i < 340; i += NT) plane[i] = 0x80808080u;
    __syncthreads();

    int lmin = 255;
    for (int i = tid; i < 576; i += NT) {
        int q = quantize(w[o * 576 + i]);
        qwrow[i] = (unsigned char)q;
        lmin = lmin < q ? lmin : q;
    }
    atomicMin(&s_min, lmin);
    __syncthreads();

    int cmin = s_min;
    if (cmin > 256 - BW1) cmin = 256 - BW1;

    for (int i = tid; i < 256 * BW1; i += NT) {
        int qx = i / BW1;
        int cc = i - qx * BW1;
        band[i] = lut[(qx << 8) + cmin + cc];
    }

    const int y  = tid >> 3;
    const int xq = tid & 7;
    const int x0 = xq << 2;

    float acc0 = 0.f, acc1 = 0.f, acc2 = 0.f, acc3 = 0.f;
    const float* xb = x + (size_t)b * 64 * 1024;
    unsigned char* pb = (unsigned char*)plane;

    for (int c = 0; c < 64; ++c) {
        __syncthreads();
        float4 xv = *(const float4*)(xb + c * 1024 + y * 32 + x0);
        int qa = quantize(xv.x), qb = quantize(xv.y);
        int qc = quantize(xv.z), qd = quantize(xv.w);
        int wbase = (y + 1) * 40 + x0 + 1;
        pb[wbase + 0] = (unsigned char)qa;
        pb[wbase + 1] = (unsigned char)qb;
        pb[wbase + 2] = (unsigned char)qc;
        pb[wbase + 3] = (unsigned char)qd;
        __syncthreads();

        const unsigned char* qwp = qwrow + c * 9;
        #pragma unroll
        for (int ky = 0; ky < 3; ++ky) {
            int ro = (y + ky) * 10 + xq;
            unsigned int r0 = plane[ro];
            unsigned int r1 = plane[ro + 1];
            int ee[6];
            ee[0] = (int)(r0 & 255u);
            ee[1] = (int)((r0 >> 8) & 255u);
            ee[2] = (int)((r0 >> 16) & 255u);
            ee[3] = (int)(r0 >> 24);
            ee[4] = (int)(r1 & 255u);
            ee[5] = (int)((r1 >> 8) & 255u);
            int pp[6];
            #pragma unroll
            for (int tt = 0; tt < 6; ++tt) pp[tt] = ee[tt] * BW1;
            #pragma unroll
            for (int kx = 0; kx < 3; ++kx) {
                int cq = (int)qwp[ky * 3 + kx];
                int cc = cq - cmin;
                if ((unsigned)cc < (unsigned)BW1) {
                    acc0 += band[pp[kx + 0] + cc];
                    acc1 += band[pp[kx + 1] + cc];
                    acc2 += band[pp[kx + 2] + cc];
                    acc3 += band[pp[kx + 3] + cc];
                } else {
                    acc0 += lut[(ee[kx + 0] << 8) + cq];
                    acc1 += lut[(ee[kx + 1] << 8) + cq];
                    acc2 += lut[(ee[kx + 2] << 8) + cq];
                    acc3 += lut[(ee[kx + 3] << 8) + cq];
                }
            }
        }
    }

    float bo = bias[o];
    float4 r;
    r.x = acc0 + bo; r.y = acc1 + bo; r.z = acc2 + bo; r.w = acc3 + bo;
    *(float4*)(out + (size_t)bid * 1024 + y * 32 + x0) = r;
}

extern "C" void kernel_launch(void* const* d_in, const int* in_sizes, int n_in,
                              void* d_out, int out_size, void* d_ws, size_t ws_size,
                              hipStream_t stream) {
    const float* x    = (const float*)d_in[0];
    const float* wgt  = (const float*)d_in[1];
    const float* bias = (const float*)d_in[2];
    const float* lut  = (const float*)d_in[3];
    float* out = (float*)d_out;

    const size_t T_BYTES = (size_t)16 * 64 * 3 * 256 * 24;   // 18,874,368
    if (ws_size >= T_BYTES) {
        hipLaunchKernelGGL(build_T4, dim3(512), dim3(NT), 0, stream,
                           wgt, lut, (unsigned int*)d_ws);
        hipLaunchKernelGGL(approx_main, dim3(512), dim3(NT), 0, stream,
                           x, (const unsigned int*)d_ws, bias, out);
    } else {
        hipLaunchKernelGGL(approxconv2d_v1, dim3(512), dim3(NT), 0, stream,
                           x, wgt, bias, lut, out);
    }
}